// Round 1
// baseline (45.585 us; speedup 1.0000x reference)
//
#include <hip/hip_runtime.h>

// Reference reduces to elementwise: out = x + x * sigmoid(2x).
// All attention/conv params are dead code (both att() and att2() return
// their input in the source). Pure memory-bound map over 2^25 f32 elems.

__global__ __launch_bounds__(256) void TH_38783554683567_kernel(
        const float4* __restrict__ x, float4* __restrict__ out, int n4) {
    int idx = blockIdx.x * blockDim.x + threadIdx.x;
    int stride = gridDim.x * blockDim.x;
    for (int i = idx; i < n4; i += stride) {
        float4 v = x[i];
        float4 r;
        // out = x * (1 + sigmoid(2x)); sigmoid(2x) = 1/(1+exp(-2x))
        r.x = v.x + v.x * (1.0f / (1.0f + __expf(-2.0f * v.x)));
        r.y = v.y + v.y * (1.0f / (1.0f + __expf(-2.0f * v.y)));
        r.z = v.z + v.z * (1.0f / (1.0f + __expf(-2.0f * v.z)));
        r.w = v.w + v.w * (1.0f / (1.0f + __expf(-2.0f * v.w)));
        out[i] = r;
    }
}

extern "C" void kernel_launch(void* const* d_in, const int* in_sizes, int n_in,
                              void* d_out, int out_size, void* d_ws, size_t ws_size,
                              hipStream_t stream) {
    const float4* x = (const float4*)d_in[0];
    float4* out = (float4*)d_out;
    int n = in_sizes[0];          // 128*64*64*64 = 33,554,432 (divisible by 4)
    int n4 = n >> 2;              // 8,388,608 float4s

    const int block = 256;
    // Memory-bound: cap grid at ~8 blocks/CU * 256 CUs and grid-stride.
    int grid = (n4 + block - 1) / block;
    if (grid > 2048) grid = 2048;

    TH_38783554683567_kernel<<<grid, block, 0, stream>>>(x, out, n4);
}

// Round 3
// 45.233 us; speedup vs baseline: 1.0078x; 1.0078x over previous
//
#include <hip/hip_runtime.h>

// Reference reduces to elementwise: out = x + x * sigmoid(2x).
// Pure memory-bound stream: 134 MB in + 134 MB out. Zero reuse ->
// non-temporal load/store hints to bypass L2 allocation churn.
// NT builtins need a NATIVE vector type (not HIP_vector_type), so use
// ext_vector_type(4) float -- same 16B layout as float4.

typedef float f32x4 __attribute__((ext_vector_type(4)));

__global__ __launch_bounds__(256) void TH_38783554683567_kernel(
        const f32x4* __restrict__ x, f32x4* __restrict__ out, int n4) {
    int i = blockIdx.x * blockDim.x + threadIdx.x;
    if (i < n4) {
        f32x4 v = __builtin_nontemporal_load(&x[i]);
        f32x4 r;
        r.x = v.x + v.x * (1.0f / (1.0f + __expf(-2.0f * v.x)));
        r.y = v.y + v.y * (1.0f / (1.0f + __expf(-2.0f * v.y)));
        r.z = v.z + v.z * (1.0f / (1.0f + __expf(-2.0f * v.z)));
        r.w = v.w + v.w * (1.0f / (1.0f + __expf(-2.0f * v.w)));
        __builtin_nontemporal_store(r, &out[i]);
    }
}

extern "C" void kernel_launch(void* const* d_in, const int* in_sizes, int n_in,
                              void* d_out, int out_size, void* d_ws, size_t ws_size,
                              hipStream_t stream) {
    const f32x4* x = (const f32x4*)d_in[0];
    f32x4* out = (f32x4*)d_out;
    int n = in_sizes[0];          // 33,554,432
    int n4 = n >> 2;              // 8,388,608 f32x4s

    const int block = 256;
    int grid = (n4 + block - 1) / block;   // 32768 blocks, exact coverage

    TH_38783554683567_kernel<<<grid, block, 0, stream>>>(x, out, n4);
}